// Round 9
// baseline (545.299 us; speedup 1.0000x reference)
//
#include <hip/hip_runtime.h>
#include <math.h>

#define B_    16
#define N_    1024
#define G_    32      // blocks per batch (R14: 2 blocks/CU overlap)
#define NW    8       // waves per block
#define ITERS 100

typedef __attribute__((ext_vector_type(2))) float f32x2;

// ws layout: [cnt: B_*ITERS u32, pad to 8192][mu_den: 4*B_*N_ f32][nug: B_*N_ f32]
#define MUDEN_OFF   8192
#define MUDEN_BYTES (4 * B_ * N_ * 4)
#define NUG_OFF     (MUDEN_OFF + MUDEN_BYTES)
#define ZERO_BYTES  NUG_OFF     // cnt + all 4 mu_den buffers start at 0

__device__ __forceinline__ float fast_div(float num, float den) {
    float r = __builtin_amdgcn_rcpf(den);
    r = r * (2.0f - den * r);      // one Newton step -> ~full fp32 accuracy
    return num * r;
}

// Full 64-lane wave sum via DPP (zero DS-pipe ops, pure VALU). Proven R1-R8.
__device__ __forceinline__ float wave_sum64(float x) {
#define DPP_ADD(ctrl)                                                   \
    x += __int_as_float(__builtin_amdgcn_update_dpp(                    \
            0, __float_as_int(x), ctrl, 0xf, 0xf, false));
    DPP_ADD(0x111)  // row_shr:1
    DPP_ADD(0x112)  // row_shr:2
    DPP_ADD(0x114)  // row_shr:4
    DPP_ADD(0x118)  // row_shr:8
    DPP_ADD(0x142)  // row_bcast:15
    DPP_ADD(0x143)  // row_bcast:31
#undef DPP_ADD
    return __int_as_float(__builtin_amdgcn_readlane(__float_as_int(x), 63));
}

// R14: clean 2-blocks/CU test. R9's regression bundled three defects later
// isolated (bank-conflicted slab, latency-bound narrow gather = R10's defect,
// doubled barrier domain) -- the overlap idea itself was never cleanly tried.
// Here: 512 blocks x 512 threads, 4 rows/wave (u2[4][8]=64 regs -- the
// R8-proven no-AGPR shape; R12/R13's 128-float u triggers arch/acc splitting
// and ~0.2us/iter of v_accvgpr_read at ANY launch_bounds). All phases keep
// proven forms: pk_fma PhiA/PhiB (R13), b128 lane-contiguous LDS (R9 lesson),
// WIDE scalar gather (R10 lesson), contiguous atomics (R7 lesson), counter
// barrier (R11 lesson). Batch map b = 2*(bid&7) + (bid>>8):
//   - each batch's 32 blocks in one XCD (L2 locality)
//   - any 256-block prefix holds WHOLE batches -> deadlock-free even if only
//     1 block/CU resident (two sequential half-grids still complete)
//   - at 2 blocks/CU the co-resident pair is from DIFFERENT batches ->
//     independent barrier domains: one block's exchange stall is filled by
//     the other's PhiA/PhiB/gather issue.
// __launch_bounds__(512,4): k = 4*4/(512/64) = 2 blocks/CU, 128-reg cap.
// Ordering (validated R4/R5/R8): __syncthreads() drains vmcnt per wave before
// s_barrier, so atomics are at the L2 coherence point before tid 0's arrival
// add; readers use coherent atomic loads only after the poll sees 32 arrivals.
__global__ __launch_bounds__(512, 4)
void sinkhorn_kernel(const float* __restrict__ C, float* __restrict__ out,
                     float* __restrict__ mu_den, float* __restrict__ nug,
                     unsigned int* __restrict__ cnt)
{
    __shared__ float part[NW * 1024];   // 32 KB: per-wave column-partial slabs
    __shared__ float mu_s[N_];          // 4 KB: current mu

    const int tid = threadIdx.x;
    const int w   = tid >> 6;        // wave 0..7 -> 4-row group
    const int l   = tid & 63;
    const int bid = blockIdx.x;
    const int b = 2 * (bid & 7) + (bid >> 8);    // batch 0..15
    const int g = (bid >> 3) & 31;               // row-group 0..31 in batch
    const int row0 = 32 * g + 4 * w;
    const float cons = 1.0f / 1024.0f;

    // ---- one-time: U tile = exp(-C/eps), columns 4*l + s + 256*ch ----
    // u2[rr][2*ch] = {U(rr,4ch+0),U(rr,4ch+1)}, u2[rr][2*ch+1] = {.,+2,.,+3}
    f32x2 u2[4][8];
    {
        const float* Cb = C + (size_t)b * N_ * N_ + (size_t)row0 * N_;
        #pragma unroll
        for (int rr = 0; rr < 4; ++rr)
            #pragma unroll
            for (int ch = 0; ch < 4; ++ch) {
                float4 cv = *(const float4*)(Cb + (size_t)rr * N_ + 4 * l + 256 * ch);
                u2[rr][2*ch]   = (f32x2){expf(-20.0f * cv.x), expf(-20.0f * cv.y)};
                u2[rr][2*ch+1] = (f32x2){expf(-20.0f * cv.z), expf(-20.0f * cv.w)};
            }
    }

    mu_s[tid]       = cons;
    mu_s[tid + 512] = cons;
    __syncthreads();

    for (int it = 0; it < ITERS; ++it) {
        // ---- Phase A: s_i = sum_j U_ij * mu_j (4x ds_read_b128 + pk-fma) ----
        f32x2 a20 = (f32x2){0.f, 0.f}, a21 = (f32x2){0.f, 0.f};
        f32x2 a22 = (f32x2){0.f, 0.f}, a23 = (f32x2){0.f, 0.f};
        #pragma unroll
        for (int ch = 0; ch < 4; ++ch) {
            float4 mv = *(const float4*)&mu_s[4 * l + 256 * ch];
            const f32x2 m01 = (f32x2){mv.x, mv.y};
            const f32x2 m23 = (f32x2){mv.z, mv.w};
            a20 += u2[0][2*ch] * m01;  a20 += u2[0][2*ch+1] * m23;
            a21 += u2[1][2*ch] * m01;  a21 += u2[1][2*ch+1] * m23;
            a22 += u2[2][2*ch] * m01;  a22 += u2[2][2*ch+1] * m23;
            a23 += u2[3][2*ch] * m01;  a23 += u2[3][2*ch+1] * m23;
        }
        float a0 = wave_sum64(a20.x + a20.y);
        float a1 = wave_sum64(a21.x + a21.y);
        float a2 = wave_sum64(a22.x + a22.y);
        float a3 = wave_sum64(a23.x + a23.y);
        float nu0 = fast_div(cons, a0), nu1 = fast_div(cons, a1);
        float nu2 = fast_div(cons, a2), nu3 = fast_div(cons, a3);

        if (it == ITERS - 1 && l < 4) {   // publish final nu chunk (coherent)
            float nv = (l == 0) ? nu0 : (l == 1) ? nu1 : (l == 2) ? nu2 : nu3;
            __hip_atomic_store(&nug[b * N_ + row0 + l], nv,
                               __ATOMIC_RELAXED, __HIP_MEMORY_SCOPE_AGENT);
        }

        const f32x2 nr0 = (f32x2){nu0, nu0}, nr1 = (f32x2){nu1, nu1};
        const f32x2 nr2 = (f32x2){nu2, nu2}, nr3 = (f32x2){nu3, nu3};

        // ---- Phase B: per-wave column partials -> slab (4x ds_write_b128,
        //      lane-contiguous 16B stride; pk-fma) ----
        // (no sync needed before this: iter it-1's gather reads finished
        //  before S2 of it-1 < here; part[] and mu_s[] are separate arrays)
        #pragma unroll
        for (int ch = 0; ch < 4; ++ch) {
            f32x2 pxy = u2[0][2*ch] * nr0;
            pxy += u2[1][2*ch] * nr1;
            pxy += u2[2][2*ch] * nr2;
            pxy += u2[3][2*ch] * nr3;
            f32x2 pzw = u2[0][2*ch+1] * nr0;
            pzw += u2[1][2*ch+1] * nr1;
            pzw += u2[2][2*ch+1] * nr2;
            pzw += u2[3][2*ch+1] * nr3;
            float4 p;
            p.x = pxy.x; p.y = pxy.y; p.z = pzw.x; p.w = pzw.y;
            *(float4*)&part[w * 1024 + 4 * l + 256 * ch] = p;
        }
        __syncthreads();   // S1: slabs complete

        // column sums across 8 slabs (WIDE: all 512 threads, conflict-free
        // b32, 2 columns each); TWO contiguous f32 atomics per thread
        const int buf = it & 3;
        {
            float s0 = 0.f, s1 = 0.f;
            #pragma unroll
            for (int w2 = 0; w2 < NW; ++w2) {
                s0 += part[w2 * 1024 + tid];
                s1 += part[w2 * 1024 + tid + 512];
            }
            float* md = &mu_den[((size_t)buf * B_ + b) * N_];
            unsafeAtomicAdd(md + tid,       s0);
            unsafeAtomicAdd(md + tid + 512, s1);
        }

        // ---- fence-free device barrier among the 32 blocks of batch b ----
        __syncthreads();   // S2: each wave's vmcnt(0) -> adds at coherence pt
        if (tid == 0) {
            unsigned int* c = &cnt[b * ITERS + it];
            __hip_atomic_fetch_add(c, 1u, __ATOMIC_RELAXED, __HIP_MEMORY_SCOPE_AGENT);
            while (__hip_atomic_load(c, __ATOMIC_RELAXED, __HIP_MEMORY_SCOPE_AGENT) < G_)
                __builtin_amdgcn_s_sleep(1);
        }
        __syncthreads();   // S3

        // ---- readback -> new mu; zero the buffer for iter it+2 ----
        {
            const float* mdb = &mu_den[((size_t)buf * B_ + b) * N_];
            float den0 = __hip_atomic_load(mdb + tid,
                                           __ATOMIC_RELAXED, __HIP_MEMORY_SCOPE_AGENT);
            float den1 = __hip_atomic_load(mdb + tid + 512,
                                           __ATOMIC_RELAXED, __HIP_MEMORY_SCOPE_AGENT);
            mu_s[tid]       = fast_div(cons, den0);
            mu_s[tid + 512] = fast_div(cons, den1);
        }
        if (tid < 32)   // my block's 1/32 share of the buffer reused at it+2
            __hip_atomic_store(&mu_den[((size_t)((it + 2) & 3) * B_ + b) * N_ + 32 * g + tid],
                               0.0f, __ATOMIC_RELAXED, __HIP_MEMORY_SCOPE_AGENT);
        __syncthreads();   // S4: mu_s ready for next phase A
    }

    // ---- epilogue: T_ij = mu_i * U_ij * nu_j (float4 stores) ----
    float mu_i[4];
    #pragma unroll
    for (int rr = 0; rr < 4; ++rr)
        mu_i[rr] = mu_s[row0 + rr];          // broadcast read

    float* ob = out + (size_t)b * N_ * N_ + (size_t)row0 * N_;
    #pragma unroll
    for (int ch = 0; ch < 4; ++ch) {
        const int cbase = b * N_ + 4 * l + 256 * ch;
        float4 nuv;
        nuv.x = __hip_atomic_load(&nug[cbase + 0], __ATOMIC_RELAXED, __HIP_MEMORY_SCOPE_AGENT);
        nuv.y = __hip_atomic_load(&nug[cbase + 1], __ATOMIC_RELAXED, __HIP_MEMORY_SCOPE_AGENT);
        nuv.z = __hip_atomic_load(&nug[cbase + 2], __ATOMIC_RELAXED, __HIP_MEMORY_SCOPE_AGENT);
        nuv.w = __hip_atomic_load(&nug[cbase + 3], __ATOMIC_RELAXED, __HIP_MEMORY_SCOPE_AGENT);
        const f32x2 nv01 = (f32x2){nuv.x, nuv.y};
        const f32x2 nv23 = (f32x2){nuv.z, nuv.w};
        #pragma unroll
        for (int rr = 0; rr < 4; ++rr) {
            const f32x2 mu2v = (f32x2){mu_i[rr], mu_i[rr]};
            f32x2 t01 = mu2v * u2[rr][2*ch]   * nv01;
            f32x2 t23 = mu2v * u2[rr][2*ch+1] * nv23;
            float4 t;
            t.x = t01.x; t.y = t01.y; t.z = t23.x; t.w = t23.y;
            *(float4*)(ob + (size_t)rr * N_ + 4 * l + 256 * ch) = t;
        }
    }
}

extern "C" void kernel_launch(void* const* d_in, const int* in_sizes, int n_in,
                              void* d_out, int out_size, void* d_ws, size_t ws_size,
                              hipStream_t stream) {
    const float* C = (const float*)d_in[2];     // (B, N, N); x,y unused
    float* out = (float*)d_out;

    unsigned char* ws = (unsigned char*)d_ws;
    unsigned int* cnt = (unsigned int*)ws;
    float* mu_den = (float*)(ws + MUDEN_OFF);
    float* nug    = (float*)(ws + NUG_OFF);

    // cnt + mu_den buffers must start at zero (buffers 2,3 are re-zeroed
    // in-kernel during iters 0,1 as part of the rotation anyway)
    hipMemsetAsync(ws, 0, ZERO_BYTES, stream);
    hipLaunchKernelGGL(sinkhorn_kernel, dim3(512), dim3(512), 0, stream,
                       C, out, mu_den, nug, cnt);
}

// Round 10
// 454.242 us; speedup vs baseline: 1.2005x; 1.2005x over previous
//
#include <hip/hip_runtime.h>
#include <math.h>

#define B_    16
#define N_    1024
#define G_    32      // blocks per batch barrier domain (one XCD's 32 blocks)
#define NW    8       // waves per block
#define ITERS 100

typedef __attribute__((ext_vector_type(2))) float f32x2;

// ws layout: [cnt: B_*ITERS u32, pad to 8192][mu_den: 4*B_*N_ f32][nug: B_*N_ f32]
#define MUDEN_OFF   8192
#define MUDEN_BYTES (4 * B_ * N_ * 4)
#define NUG_OFF     (MUDEN_OFF + MUDEN_BYTES)
#define ZERO_BYTES  NUG_OFF     // cnt + all 4 mu_den buffers start at 0

__device__ __forceinline__ float fast_div(float num, float den) {
    float r = __builtin_amdgcn_rcpf(den);
    r = r * (2.0f - den * r);      // one Newton step -> ~full fp32 accuracy
    return num * r;
}

// Full 64-lane wave sum via DPP (zero DS-pipe ops, pure VALU). Proven R1-R9.
__device__ __forceinline__ float wave_sum64(float x) {
#define DPP_ADD(ctrl)                                                   \
    x += __int_as_float(__builtin_amdgcn_update_dpp(                    \
            0, __float_as_int(x), ctrl, 0xf, 0xf, false));
    DPP_ADD(0x111)  // row_shr:1
    DPP_ADD(0x112)  // row_shr:2
    DPP_ADD(0x114)  // row_shr:4
    DPP_ADD(0x118)  // row_shr:8
    DPP_ADD(0x142)  // row_bcast:15
    DPP_ADD(0x143)  // row_bcast:31
#undef DPP_ADD
    return __int_as_float(__builtin_amdgcn_readlane(__float_as_int(x), 63));
}

// R15: TWO-BATCH SOFTWARE PIPELINE. R9+R14 proved cross-block overlap via the
// CU scheduler is unobtainable (co-resident blocks convoy, VALUBusy 43->22).
// So overlap INSIDE the wave instead: each block owns 32 rows of batch bA and
// 32 rows of bB (both on its XCD). Per iteration, program order is
//   compute+gather+arrive(A) ; compute+gather+arrive(B) ; poll A (aged one
//   full compute phase -> immediate) ; poll B ; combined readback (4 parallel
//   L2 loads).
// A's exchange round-trip (~0.45us) hides under B's compute; per-wave ILP
// doubles (two independent dep chains). Slab LDS is time-shared: gather(A)
// reads complete before S2, PhiB(B) writes after S2. Deadlock-safe: grid =
// 256 = #CUs -> 1 block/CU, all resident; arrivals are non-blocking and
// strictly precede all polls.
// All phase implementations keep proven forms: pk_fma PhiA/PhiB (R13), b128
// lane-contiguous LDS (R9 lesson), wide scalar gather (R10 lesson), counter
// barrier (R11 lesson), contiguous atomics (R7 lesson).
// Ordering (validated R4/R5/R8): __syncthreads() drains vmcnt per wave before
// s_barrier, so atomics are at the L2 coherence point before tid 0's arrival
// add; readers use coherent atomic loads only after the poll sees 32 arrivals.
__global__ __launch_bounds__(512, 1)
void sinkhorn_kernel(const float* __restrict__ C, float* __restrict__ out,
                     float* __restrict__ mu_den, float* __restrict__ nug,
                     unsigned int* __restrict__ cnt)
{
    __shared__ float part[NW * 1024];   // 32 KB: slabs, time-shared A then B
    __shared__ float mu_sA[N_];         // 4 KB
    __shared__ float mu_sB[N_];         // 4 KB

    const int tid = threadIdx.x;
    const int w   = tid >> 6;        // wave 0..7 -> 4-row group per stream
    const int l   = tid & 63;
    const int bid = blockIdx.x;
    const int bA  = 2 * (bid & 7);   // even batch of this XCD
    const int bB  = bA + 1;          // odd batch of this XCD
    const int g   = bid >> 3;        // 0..31: row-group in each batch
    const int row0 = 32 * g + 4 * w;
    const float cons = 1.0f / 1024.0f;

    // ---- one-time: U tiles = exp(-C/eps), columns 4*l + s + 256*ch ----
    f32x2 uA[4][8], uB[4][8];
    {
        const float* CA = C + (size_t)bA * N_ * N_ + (size_t)row0 * N_;
        const float* CB = C + (size_t)bB * N_ * N_ + (size_t)row0 * N_;
        #pragma unroll
        for (int rr = 0; rr < 4; ++rr)
            #pragma unroll
            for (int ch = 0; ch < 4; ++ch) {
                float4 ca = *(const float4*)(CA + (size_t)rr * N_ + 4 * l + 256 * ch);
                float4 cb = *(const float4*)(CB + (size_t)rr * N_ + 4 * l + 256 * ch);
                uA[rr][2*ch]   = (f32x2){expf(-20.0f * ca.x), expf(-20.0f * ca.y)};
                uA[rr][2*ch+1] = (f32x2){expf(-20.0f * ca.z), expf(-20.0f * ca.w)};
                uB[rr][2*ch]   = (f32x2){expf(-20.0f * cb.x), expf(-20.0f * cb.y)};
                uB[rr][2*ch+1] = (f32x2){expf(-20.0f * cb.z), expf(-20.0f * cb.w)};
            }
    }

    mu_sA[tid] = cons;  mu_sA[tid + 512] = cons;
    mu_sB[tid] = cons;  mu_sB[tid + 512] = cons;
    __syncthreads();

    for (int it = 0; it < ITERS; ++it) {
        const int buf = it & 3;

        // ================= stream A =================
        {
            // Phase A: 4x ds_read_b128 + pk-fma
            f32x2 q0 = (f32x2){0.f,0.f}, q1 = (f32x2){0.f,0.f};
            f32x2 q2 = (f32x2){0.f,0.f}, q3 = (f32x2){0.f,0.f};
            #pragma unroll
            for (int ch = 0; ch < 4; ++ch) {
                float4 mv = *(const float4*)&mu_sA[4 * l + 256 * ch];
                const f32x2 m01 = (f32x2){mv.x, mv.y};
                const f32x2 m23 = (f32x2){mv.z, mv.w};
                q0 += uA[0][2*ch] * m01;  q0 += uA[0][2*ch+1] * m23;
                q1 += uA[1][2*ch] * m01;  q1 += uA[1][2*ch+1] * m23;
                q2 += uA[2][2*ch] * m01;  q2 += uA[2][2*ch+1] * m23;
                q3 += uA[3][2*ch] * m01;  q3 += uA[3][2*ch+1] * m23;
            }
            float nu0 = fast_div(cons, wave_sum64(q0.x + q0.y));
            float nu1 = fast_div(cons, wave_sum64(q1.x + q1.y));
            float nu2 = fast_div(cons, wave_sum64(q2.x + q2.y));
            float nu3 = fast_div(cons, wave_sum64(q3.x + q3.y));

            if (it == ITERS - 1 && l < 4) {   // publish final nu chunk
                float nv = (l == 0) ? nu0 : (l == 1) ? nu1 : (l == 2) ? nu2 : nu3;
                __hip_atomic_store(&nug[bA * N_ + row0 + l], nv,
                                   __ATOMIC_RELAXED, __HIP_MEMORY_SCOPE_AGENT);
            }
            const f32x2 n0 = (f32x2){nu0,nu0}, n1 = (f32x2){nu1,nu1};
            const f32x2 n2 = (f32x2){nu2,nu2}, n3 = (f32x2){nu3,nu3};

            // Phase B: slab writes (lane-contiguous b128). Safe: last reader
            // of part was gather(B) of it-1, completed before S2' of it-1.
            #pragma unroll
            for (int ch = 0; ch < 4; ++ch) {
                f32x2 pxy = uA[0][2*ch] * n0;
                pxy += uA[1][2*ch] * n1;  pxy += uA[2][2*ch] * n2;
                pxy += uA[3][2*ch] * n3;
                f32x2 pzw = uA[0][2*ch+1] * n0;
                pzw += uA[1][2*ch+1] * n1; pzw += uA[2][2*ch+1] * n2;
                pzw += uA[3][2*ch+1] * n3;
                float4 p; p.x = pxy.x; p.y = pxy.y; p.z = pzw.x; p.w = pzw.y;
                *(float4*)&part[w * 1024 + 4 * l + 256 * ch] = p;
            }
        }
        __syncthreads();   // S1: A-slabs complete

        {   // wide gather (all 512 threads, conflict-free b32) + contiguous atomics
            float s0 = 0.f, s1 = 0.f;
            #pragma unroll
            for (int w2 = 0; w2 < NW; ++w2) {
                s0 += part[w2 * 1024 + tid];
                s1 += part[w2 * 1024 + tid + 512];
            }
            float* md = &mu_den[((size_t)buf * B_ + bA) * N_];
            unsafeAtomicAdd(md + tid,       s0);
            unsafeAtomicAdd(md + tid + 512, s1);
        }
        __syncthreads();   // S2: A atomics at coherence point; gather(A) done
        if (tid == 0)      // non-blocking arrival A
            __hip_atomic_fetch_add(&cnt[bA * ITERS + it], 1u,
                                   __ATOMIC_RELAXED, __HIP_MEMORY_SCOPE_AGENT);

        // ================= stream B (hides A's exchange) =================
        {
            f32x2 q0 = (f32x2){0.f,0.f}, q1 = (f32x2){0.f,0.f};
            f32x2 q2 = (f32x2){0.f,0.f}, q3 = (f32x2){0.f,0.f};
            #pragma unroll
            for (int ch = 0; ch < 4; ++ch) {
                float4 mv = *(const float4*)&mu_sB[4 * l + 256 * ch];
                const f32x2 m01 = (f32x2){mv.x, mv.y};
                const f32x2 m23 = (f32x2){mv.z, mv.w};
                q0 += uB[0][2*ch] * m01;  q0 += uB[0][2*ch+1] * m23;
                q1 += uB[1][2*ch] * m01;  q1 += uB[1][2*ch+1] * m23;
                q2 += uB[2][2*ch] * m01;  q2 += uB[2][2*ch+1] * m23;
                q3 += uB[3][2*ch] * m01;  q3 += uB[3][2*ch+1] * m23;
            }
            float nu0 = fast_div(cons, wave_sum64(q0.x + q0.y));
            float nu1 = fast_div(cons, wave_sum64(q1.x + q1.y));
            float nu2 = fast_div(cons, wave_sum64(q2.x + q2.y));
            float nu3 = fast_div(cons, wave_sum64(q3.x + q3.y));

            if (it == ITERS - 1 && l < 4) {
                float nv = (l == 0) ? nu0 : (l == 1) ? nu1 : (l == 2) ? nu2 : nu3;
                __hip_atomic_store(&nug[bB * N_ + row0 + l], nv,
                                   __ATOMIC_RELAXED, __HIP_MEMORY_SCOPE_AGENT);
            }
            const f32x2 n0 = (f32x2){nu0,nu0}, n1 = (f32x2){nu1,nu1};
            const f32x2 n2 = (f32x2){nu2,nu2}, n3 = (f32x2){nu3,nu3};

            // Phase B(B): overwrites part -- safe, all waves passed S2
            #pragma unroll
            for (int ch = 0; ch < 4; ++ch) {
                f32x2 pxy = uB[0][2*ch] * n0;
                pxy += uB[1][2*ch] * n1;  pxy += uB[2][2*ch] * n2;
                pxy += uB[3][2*ch] * n3;
                f32x2 pzw = uB[0][2*ch+1] * n0;
                pzw += uB[1][2*ch+1] * n1; pzw += uB[2][2*ch+1] * n2;
                pzw += uB[3][2*ch+1] * n3;
                float4 p; p.x = pxy.x; p.y = pxy.y; p.z = pzw.x; p.w = pzw.y;
                *(float4*)&part[w * 1024 + 4 * l + 256 * ch] = p;
            }
        }
        __syncthreads();   // S1': B-slabs complete

        {
            float s0 = 0.f, s1 = 0.f;
            #pragma unroll
            for (int w2 = 0; w2 < NW; ++w2) {
                s0 += part[w2 * 1024 + tid];
                s1 += part[w2 * 1024 + tid + 512];
            }
            float* md = &mu_den[((size_t)buf * B_ + bB) * N_];
            unsafeAtomicAdd(md + tid,       s0);
            unsafeAtomicAdd(md + tid + 512, s1);
        }
        __syncthreads();   // S2': B atomics at coherence point
        if (tid == 0) {
            __hip_atomic_fetch_add(&cnt[bB * ITERS + it], 1u,
                                   __ATOMIC_RELAXED, __HIP_MEMORY_SCOPE_AGENT);
            // poll A: aged one full compute phase -> usually immediate
            unsigned int* cA = &cnt[bA * ITERS + it];
            while (__hip_atomic_load(cA, __ATOMIC_RELAXED, __HIP_MEMORY_SCOPE_AGENT) < G_)
                __builtin_amdgcn_s_sleep(1);
            unsigned int* cB = &cnt[bB * ITERS + it];
            while (__hip_atomic_load(cB, __ATOMIC_RELAXED, __HIP_MEMORY_SCOPE_AGENT) < G_)
                __builtin_amdgcn_s_sleep(1);
        }
        __syncthreads();   // S3: both exchanges complete

        // ---- combined readback (4 parallel L2 loads) -> new mu; zeroing ----
        {
            const float* mA = &mu_den[((size_t)buf * B_ + bA) * N_];
            const float* mB = &mu_den[((size_t)buf * B_ + bB) * N_];
            float dA0 = __hip_atomic_load(mA + tid,       __ATOMIC_RELAXED, __HIP_MEMORY_SCOPE_AGENT);
            float dA1 = __hip_atomic_load(mA + tid + 512, __ATOMIC_RELAXED, __HIP_MEMORY_SCOPE_AGENT);
            float dB0 = __hip_atomic_load(mB + tid,       __ATOMIC_RELAXED, __HIP_MEMORY_SCOPE_AGENT);
            float dB1 = __hip_atomic_load(mB + tid + 512, __ATOMIC_RELAXED, __HIP_MEMORY_SCOPE_AGENT);
            mu_sA[tid]       = fast_div(cons, dA0);
            mu_sA[tid + 512] = fast_div(cons, dA1);
            mu_sB[tid]       = fast_div(cons, dB0);
            mu_sB[tid + 512] = fast_div(cons, dB1);
        }
        if (tid < 32) {   // my block's 1/32 share of each buffer reused at it+2
            const size_t zb = (size_t)((it + 2) & 3) * B_;
            __hip_atomic_store(&mu_den[(zb + bA) * N_ + 32 * g + tid], 0.0f,
                               __ATOMIC_RELAXED, __HIP_MEMORY_SCOPE_AGENT);
            __hip_atomic_store(&mu_den[(zb + bB) * N_ + 32 * g + tid], 0.0f,
                               __ATOMIC_RELAXED, __HIP_MEMORY_SCOPE_AGENT);
        }
        __syncthreads();   // S4: mu_sA/mu_sB ready for next iteration
    }

    // ---- epilogue: T_ij = mu_i * U_ij * nu_j for both streams ----
    float muA[4], muB[4];
    #pragma unroll
    for (int rr = 0; rr < 4; ++rr) {
        muA[rr] = mu_sA[row0 + rr];
        muB[rr] = mu_sB[row0 + rr];
    }

    float* oA = out + (size_t)bA * N_ * N_ + (size_t)row0 * N_;
    float* oB = out + (size_t)bB * N_ * N_ + (size_t)row0 * N_;
    #pragma unroll
    for (int ch = 0; ch < 4; ++ch) {
        const int cA = bA * N_ + 4 * l + 256 * ch;
        const int cB = bB * N_ + 4 * l + 256 * ch;
        float4 nA, nB;
        nA.x = __hip_atomic_load(&nug[cA + 0], __ATOMIC_RELAXED, __HIP_MEMORY_SCOPE_AGENT);
        nA.y = __hip_atomic_load(&nug[cA + 1], __ATOMIC_RELAXED, __HIP_MEMORY_SCOPE_AGENT);
        nA.z = __hip_atomic_load(&nug[cA + 2], __ATOMIC_RELAXED, __HIP_MEMORY_SCOPE_AGENT);
        nA.w = __hip_atomic_load(&nug[cA + 3], __ATOMIC_RELAXED, __HIP_MEMORY_SCOPE_AGENT);
        nB.x = __hip_atomic_load(&nug[cB + 0], __ATOMIC_RELAXED, __HIP_MEMORY_SCOPE_AGENT);
        nB.y = __hip_atomic_load(&nug[cB + 1], __ATOMIC_RELAXED, __HIP_MEMORY_SCOPE_AGENT);
        nB.z = __hip_atomic_load(&nug[cB + 2], __ATOMIC_RELAXED, __HIP_MEMORY_SCOPE_AGENT);
        nB.w = __hip_atomic_load(&nug[cB + 3], __ATOMIC_RELAXED, __HIP_MEMORY_SCOPE_AGENT);
        #pragma unroll
        for (int rr = 0; rr < 4; ++rr) {
            float4 t;
            t.x = muA[rr] * uA[rr][2*ch].x   * nA.x;
            t.y = muA[rr] * uA[rr][2*ch].y   * nA.y;
            t.z = muA[rr] * uA[rr][2*ch+1].x * nA.z;
            t.w = muA[rr] * uA[rr][2*ch+1].y * nA.w;
            *(float4*)(oA + (size_t)rr * N_ + 4 * l + 256 * ch) = t;
            t.x = muB[rr] * uB[rr][2*ch].x   * nB.x;
            t.y = muB[rr] * uB[rr][2*ch].y   * nB.y;
            t.z = muB[rr] * uB[rr][2*ch+1].x * nB.z;
            t.w = muB[rr] * uB[rr][2*ch+1].y * nB.w;
            *(float4*)(oB + (size_t)rr * N_ + 4 * l + 256 * ch) = t;
        }
    }
}

extern "C" void kernel_launch(void* const* d_in, const int* in_sizes, int n_in,
                              void* d_out, int out_size, void* d_ws, size_t ws_size,
                              hipStream_t stream) {
    const float* C = (const float*)d_in[2];     // (B, N, N); x,y unused
    float* out = (float*)d_out;

    unsigned char* ws = (unsigned char*)d_ws;
    unsigned int* cnt = (unsigned int*)ws;
    float* mu_den = (float*)(ws + MUDEN_OFF);
    float* nug    = (float*)(ws + NUG_OFF);

    // cnt + mu_den buffers must start at zero (buffers 2,3 are re-zeroed
    // in-kernel during iters 0,1 as part of the rotation anyway)
    hipMemsetAsync(ws, 0, ZERO_BYTES, stream);
    hipLaunchKernelGGL(sinkhorn_kernel, dim3(256), dim3(512), 0, stream,
                       C, out, mu_den, nug, cnt);
}

// Round 11
// 372.717 us; speedup vs baseline: 1.4630x; 1.2187x over previous
//
#include <hip/hip_runtime.h>
#include <math.h>

#define B_    16
#define N_    1024
#define G_    16      // blocks per batch
#define NW    8       // waves per block (8 rows/wave)
#define ITERS 100

typedef __attribute__((ext_vector_type(2))) float f32x2;

// ws layout: [cnt: B_*ITERS u32, pad to 8192][mu_den: 4*B_*N_ f32][nug: B_*N_ f32]
#define MUDEN_OFF   8192
#define MUDEN_BYTES (4 * B_ * N_ * 4)
#define NUG_OFF     (MUDEN_OFF + MUDEN_BYTES)
#define ZERO_BYTES  NUG_OFF     // cnt + all 4 mu_den buffers start at 0

__device__ __forceinline__ float fast_div(float num, float den) {
    float r = __builtin_amdgcn_rcpf(den);
    r = r * (2.0f - den * r);      // one Newton step -> ~full fp32 accuracy
    return num * r;
}

// Full 64-lane wave sum via DPP (zero DS-pipe ops, pure VALU). Proven R1-R10.
__device__ __forceinline__ float wave_sum64(float x) {
#define DPP_ADD(ctrl)                                                   \
    x += __int_as_float(__builtin_amdgcn_update_dpp(                    \
            0, __float_as_int(x), ctrl, 0xf, 0xf, false));
    DPP_ADD(0x111)  // row_shr:1
    DPP_ADD(0x112)  // row_shr:2
    DPP_ADD(0x114)  // row_shr:4
    DPP_ADD(0x118)  // row_shr:8
    DPP_ADD(0x142)  // row_bcast:15
    DPP_ADD(0x143)  // row_bcast:31
#undef DPP_ADD
    return __int_as_float(__builtin_amdgcn_readlane(__float_as_int(x), 63));
}

// R16 = R13 RESTORED (best measured: 278us kernel / 378us harness).
// The full falsification ledger that pins this as the structural optimum:
//   R7  strided atomics       -> 4x HBM write amplification (+92%)
//   R9  2 blk/CU (dirty)      -> convoy + bank conflicts (+70%)
//   R10 narrow b128 gather    -> latency-bound narrow phase (+55%)
//   R11 flag-vector barrier   -> +6% (exchange ~0.45us/iter in any phrasing)
//   R14 2 blk/CU (clean)      -> convoy confirmed (+66%)
//   R15 two-batch SW pipeline -> doubled gather/barrier cost > hiding (+41%)
// Structure: 8 rows/wave, 512 threads, 1 block/CU, 16 blocks/batch.
//   - pk_fma PhiA/PhiB (v_pk_fma_f32, R13: VALU 41->34%)
//   - b128 lane-contiguous LDS slab writes + mu reads (R9 lesson)
//   - WIDE scalar-b32 gather, all 512 threads (R10 lesson)
//   - contiguous global f32 atomics at tid/tid+512 (R7 lesson)
//   - counter barrier + tid0 poll (R11: cheapest phrasing)
//   - 4-buffer mu_den rotation, self-zeroing two iterations ahead
// Known cost accepted: u2[8][8]=128 floats triggers arch/acc register split
// (VGPR_Count 88 + AGPRs) -> ~0.2us/iter of v_accvgpr moves; launch_bounds
// (512,1)/(512,2) both produce it; 4-rows/wave avoids it but pays more DS
// (R8: 308us). Ledger at 2.78us/iter: VALU 0.94 + DS 0.67 + exchange 0.45 +
// latency exposure ~0.7 (resisted five distinct overlap attacks).
// Ordering (validated R4/R5/R8): __syncthreads() drains vmcnt per wave before
// s_barrier, so atomics are at the L2 coherence point before tid 0's arrival
// add; readers use coherent atomic loads only after the poll sees 16 arrivals.
__global__ __launch_bounds__(512, 1)
void sinkhorn_kernel(const float* __restrict__ C, float* __restrict__ out,
                     float* __restrict__ mu_den, float* __restrict__ nug,
                     unsigned int* __restrict__ cnt)
{
    __shared__ float part[NW * 1024];   // 32 KB: per-wave column-partial slabs
    __shared__ float mu_s[N_];          // 4 KB: current mu

    const int tid = threadIdx.x;
    const int w   = tid >> 6;        // wave 0..7 -> 8-row group
    const int l   = tid & 63;
    // XCD-affinity swizzle: batch b's 16 blocks share bid%8 -> same XCD L2
    const int bid = blockIdx.x;
    const int xx = bid & 7, ss = bid >> 3;
    const int b = xx + ((ss >> 4) << 3);
    const int g = ss & 15;
    const int row0 = 64 * g + 8 * w;
    const float cons = 1.0f / 1024.0f;

    // ---- one-time: U tile = exp(-C/eps), columns 4*l + s + 256*ch ----
    // u2[rr][2*ch]   = {U(rr, 4ch+0), U(rr, 4ch+1)}
    // u2[rr][2*ch+1] = {U(rr, 4ch+2), U(rr, 4ch+3)}
    f32x2 u2[8][8];
    {
        const float* Cb = C + (size_t)b * N_ * N_ + (size_t)row0 * N_;
        #pragma unroll
        for (int rr = 0; rr < 8; ++rr)
            #pragma unroll
            for (int ch = 0; ch < 4; ++ch) {
                float4 cv = *(const float4*)(Cb + (size_t)rr * N_ + 4 * l + 256 * ch);
                u2[rr][2*ch]   = (f32x2){expf(-20.0f * cv.x), expf(-20.0f * cv.y)};
                u2[rr][2*ch+1] = (f32x2){expf(-20.0f * cv.z), expf(-20.0f * cv.w)};
            }
    }

    mu_s[tid]       = cons;
    mu_s[tid + 512] = cons;
    __syncthreads();

    for (int it = 0; it < ITERS; ++it) {
        // ---- Phase A: s_i = sum_j U_ij * mu_j (4x ds_read_b128 + pk-fma) ----
        f32x2 a2[8];
        #pragma unroll
        for (int rr = 0; rr < 8; ++rr) a2[rr] = (f32x2){0.f, 0.f};
        #pragma unroll
        for (int ch = 0; ch < 4; ++ch) {
            float4 mv = *(const float4*)&mu_s[4 * l + 256 * ch];
            const f32x2 m01 = (f32x2){mv.x, mv.y};
            const f32x2 m23 = (f32x2){mv.z, mv.w};
            #pragma unroll
            for (int rr = 0; rr < 8; ++rr) {
                a2[rr] += u2[rr][2*ch]   * m01;   // v_pk_fma_f32
                a2[rr] += u2[rr][2*ch+1] * m23;   // v_pk_fma_f32
            }
        }
        float a0 = wave_sum64(a2[0].x + a2[0].y);
        float a1 = wave_sum64(a2[1].x + a2[1].y);
        float a3_ = 0.f;  // (names kept scalar; no dynamic indexing)
        float a2s = wave_sum64(a2[2].x + a2[2].y);
        a3_ = wave_sum64(a2[3].x + a2[3].y);
        float a4 = wave_sum64(a2[4].x + a2[4].y);
        float a5 = wave_sum64(a2[5].x + a2[5].y);
        float a6 = wave_sum64(a2[6].x + a2[6].y);
        float a7 = wave_sum64(a2[7].x + a2[7].y);
        float nu0 = fast_div(cons, a0),  nu1 = fast_div(cons, a1);
        float nu2 = fast_div(cons, a2s), nu3 = fast_div(cons, a3_);
        float nu4 = fast_div(cons, a4),  nu5 = fast_div(cons, a5);
        float nu6 = fast_div(cons, a6),  nu7 = fast_div(cons, a7);

        if (it == ITERS - 1 && l < 8) {   // publish final nu chunk (coherent)
            float nv = (l == 0) ? nu0 : (l == 1) ? nu1 : (l == 2) ? nu2 :
                       (l == 3) ? nu3 : (l == 4) ? nu4 : (l == 5) ? nu5 :
                       (l == 6) ? nu6 : nu7;
            __hip_atomic_store(&nug[b * N_ + row0 + l], nv,
                               __ATOMIC_RELAXED, __HIP_MEMORY_SCOPE_AGENT);
        }

        const f32x2 nur2[8] = {
            (f32x2){nu0, nu0}, (f32x2){nu1, nu1}, (f32x2){nu2, nu2},
            (f32x2){nu3, nu3}, (f32x2){nu4, nu4}, (f32x2){nu5, nu5},
            (f32x2){nu6, nu6}, (f32x2){nu7, nu7}};

        // ---- Phase B: per-wave column partials -> slab (4x ds_write_b128,
        //      lane-contiguous 16B stride; pk-fma accumulation) ----
        // (no sync needed before this: iter it-1's gather reads finished
        //  before S2 of it-1 < here; part[] and mu_s[] are separate arrays)
        #pragma unroll
        for (int ch = 0; ch < 4; ++ch) {
            f32x2 pxy = (f32x2){0.f, 0.f};
            f32x2 pzw = (f32x2){0.f, 0.f};
            #pragma unroll
            for (int rr = 0; rr < 8; ++rr) {
                pxy += u2[rr][2*ch]   * nur2[rr];   // v_pk_fma_f32
                pzw += u2[rr][2*ch+1] * nur2[rr];   // v_pk_fma_f32
            }
            float4 p;
            p.x = pxy.x; p.y = pxy.y; p.z = pzw.x; p.w = pzw.y;
            *(float4*)&part[w * 1024 + 4 * l + 256 * ch] = p;
        }
        __syncthreads();   // S1: slabs complete

        // column sums across 8 slabs (wide: all 8 waves, conflict-free b32,
        // 2 columns per thread); TWO contiguous f32 atomics per thread
        const int buf = it & 3;
        {
            float s0 = 0.f, s1 = 0.f;
            #pragma unroll
            for (int w2 = 0; w2 < NW; ++w2) {
                s0 += part[w2 * 1024 + tid];
                s1 += part[w2 * 1024 + tid + 512];
            }
            float* md = &mu_den[((size_t)buf * B_ + b) * N_];
            unsafeAtomicAdd(md + tid,       s0);
            unsafeAtomicAdd(md + tid + 512, s1);
        }

        // ---- fence-free device barrier among the 16 blocks of batch b ----
        __syncthreads();   // S2: each wave's vmcnt(0) -> adds at coherence pt
        if (tid == 0) {
            unsigned int* c = &cnt[b * ITERS + it];
            __hip_atomic_fetch_add(c, 1u, __ATOMIC_RELAXED, __HIP_MEMORY_SCOPE_AGENT);
            while (__hip_atomic_load(c, __ATOMIC_RELAXED, __HIP_MEMORY_SCOPE_AGENT) < G_)
                __builtin_amdgcn_s_sleep(1);
        }
        __syncthreads();   // S3

        // ---- readback -> new mu; zero the buffer for iter it+2 ----
        {
            const float* mdb = &mu_den[((size_t)buf * B_ + b) * N_];
            float den0 = __hip_atomic_load(mdb + tid,
                                           __ATOMIC_RELAXED, __HIP_MEMORY_SCOPE_AGENT);
            float den1 = __hip_atomic_load(mdb + tid + 512,
                                           __ATOMIC_RELAXED, __HIP_MEMORY_SCOPE_AGENT);
            mu_s[tid]       = fast_div(cons, den0);
            mu_s[tid + 512] = fast_div(cons, den1);
        }
        if (tid < 64)   // my block's 1/16 share of the buffer reused at it+2
            __hip_atomic_store(&mu_den[((size_t)((it + 2) & 3) * B_ + b) * N_ + 64 * g + tid],
                               0.0f, __ATOMIC_RELAXED, __HIP_MEMORY_SCOPE_AGENT);
        __syncthreads();   // S4: mu_s ready for next phase A
    }

    // ---- epilogue: T_ij = mu_i * U_ij * nu_j (float4 stores) ----
    float mu_i[8];
    #pragma unroll
    for (int rr = 0; rr < 8; ++rr)
        mu_i[rr] = mu_s[row0 + rr];          // broadcast read

    float* ob = out + (size_t)b * N_ * N_ + (size_t)row0 * N_;
    #pragma unroll
    for (int ch = 0; ch < 4; ++ch) {
        const int cbase = b * N_ + 4 * l + 256 * ch;
        float4 nuv;
        nuv.x = __hip_atomic_load(&nug[cbase + 0], __ATOMIC_RELAXED, __HIP_MEMORY_SCOPE_AGENT);
        nuv.y = __hip_atomic_load(&nug[cbase + 1], __ATOMIC_RELAXED, __HIP_MEMORY_SCOPE_AGENT);
        nuv.z = __hip_atomic_load(&nug[cbase + 2], __ATOMIC_RELAXED, __HIP_MEMORY_SCOPE_AGENT);
        nuv.w = __hip_atomic_load(&nug[cbase + 3], __ATOMIC_RELAXED, __HIP_MEMORY_SCOPE_AGENT);
        const f32x2 nv01 = (f32x2){nuv.x, nuv.y};
        const f32x2 nv23 = (f32x2){nuv.z, nuv.w};
        #pragma unroll
        for (int rr = 0; rr < 8; ++rr) {
            const f32x2 mu2 = (f32x2){mu_i[rr], mu_i[rr]};
            f32x2 t01 = mu2 * u2[rr][2*ch]   * nv01;
            f32x2 t23 = mu2 * u2[rr][2*ch+1] * nv23;
            float4 t;
            t.x = t01.x; t.y = t01.y; t.z = t23.x; t.w = t23.y;
            *(float4*)(ob + (size_t)rr * N_ + 4 * l + 256 * ch) = t;
        }
    }
}

extern "C" void kernel_launch(void* const* d_in, const int* in_sizes, int n_in,
                              void* d_out, int out_size, void* d_ws, size_t ws_size,
                              hipStream_t stream) {
    const float* C = (const float*)d_in[2];     // (B, N, N); x,y unused
    float* out = (float*)d_out;

    unsigned char* ws = (unsigned char*)d_ws;
    unsigned int* cnt = (unsigned int*)ws;
    float* mu_den = (float*)(ws + MUDEN_OFF);
    float* nug    = (float*)(ws + NUG_OFF);

    // cnt + mu_den buffers must start at zero (buffers 2,3 are re-zeroed
    // in-kernel during iters 0,1 as part of the rotation anyway)
    hipMemsetAsync(ws, 0, ZERO_BYTES, stream);
    hipLaunchKernelGGL(sinkhorn_kernel, dim3(256), dim3(512), 0, stream,
                       C, out, mu_den, nug, cnt);
}